// Round 1
// baseline (1283.857 us; speedup 1.0000x reference)
//
#include <hip/hip_runtime.h>

// ReBASED parallel attention, fp32 baseline (flash-style, causal, squared scores).
// B=4 H=16 S=2048 D=64. grid=(S/BQ, B*H), block=256.

#define SEQ 2048
#define HD  64
#define BQ  64
#define BK  64
#define LDT 68   // padded leading dim (multiple of 4 floats -> float4-aligned rows)

__global__ __launch_bounds__(256, 2)
void rebased_fp32_kernel(const float* __restrict__ qg,
                         const float* __restrict__ kg,
                         const float* __restrict__ vg,
                         float* __restrict__ og) {
    __shared__ float Qt[HD][LDT];   // Qt[d][i], Q transposed + pre-scaled
    __shared__ float Kt[HD][LDT];   // Kt[d][j]
    __shared__ float Vs[BK][HD];    // Vs[j][d]
    __shared__ float S2[BQ][LDT];   // squared+masked scores
    __shared__ float Zrow[BQ];

    const int t  = threadIdx.x;
    const int ti = t & 15;          // row group (16)
    const int tj = t >> 4;          // col group (16)
    const int qt = blockIdx.x;
    const int head = blockIdx.y;
    const size_t base = (size_t)head * SEQ * HD;

    // ---- stage Q tile: transpose + fold in scale = D^-0.5 = 0.125 ----
    {
        const float4* qsrc = (const float4*)(qg + base + (size_t)qt * BQ * HD);
        #pragma unroll
        for (int l = 0; l < 4; ++l) {
            int f   = t + l * 256;      // float4 index in 64x64 tile
            int row = f >> 4;           // 16 float4 per row
            int d4  = (f & 15) << 2;
            float4 val = qsrc[f];
            Qt[d4+0][row] = val.x * 0.125f;
            Qt[d4+1][row] = val.y * 0.125f;
            Qt[d4+2][row] = val.z * 0.125f;
            Qt[d4+3][row] = val.w * 0.125f;
        }
    }

    float oacc[4][4];
    #pragma unroll
    for (int u = 0; u < 4; ++u)
        #pragma unroll
        for (int c = 0; c < 4; ++c) oacc[u][c] = 0.f;
    float zacc[4] = {0.f, 0.f, 0.f, 0.f};

    for (int kt = 0; kt <= qt; ++kt) {
        __syncthreads();   // previous phase-2 done (also covers initial Q stage)

        // ---- stage K (transposed) and V ----
        {
            const float4* ksrc = (const float4*)(kg + base + (size_t)kt * BK * HD);
            const float4* vsrc = (const float4*)(vg + base + (size_t)kt * BK * HD);
            float4* vdst = (float4*)&Vs[0][0];
            #pragma unroll
            for (int l = 0; l < 4; ++l) {
                int f   = t + l * 256;
                int row = f >> 4;
                int d4  = (f & 15) << 2;
                float4 kval = ksrc[f];
                Kt[d4+0][row] = kval.x;
                Kt[d4+1][row] = kval.y;
                Kt[d4+2][row] = kval.z;
                Kt[d4+3][row] = kval.w;
                vdst[f] = vsrc[f];
            }
        }
        __syncthreads();

        // ---- phase 1: score tile, 4x4 microtile per thread ----
        float acc[4][4];
        #pragma unroll
        for (int u = 0; u < 4; ++u)
            #pragma unroll
            for (int v = 0; v < 4; ++v) acc[u][v] = 0.f;

        #pragma unroll 4
        for (int d = 0; d < HD; ++d) {
            float qa[4], kb[4];
            *(float4*)qa = *(const float4*)&Qt[d][ti << 2];
            *(float4*)kb = *(const float4*)&Kt[d][tj << 2];
            #pragma unroll
            for (int u = 0; u < 4; ++u)
                #pragma unroll
                for (int v = 0; v < 4; ++v)
                    acc[u][v] += qa[u] * kb[v];
        }

        // square + causal mask (diagonal tile only) + write to LDS
        const bool diag = (kt == qt);
        #pragma unroll
        for (int u = 0; u < 4; ++u) {
            float s2row[4];
            #pragma unroll
            for (int v = 0; v < 4; ++v) {
                float s = acc[u][v];
                float p = s * s;
                if (diag && ((tj << 2) + v > (ti << 2) + u)) p = 0.f;
                s2row[v] = p;
            }
            *(float4*)&S2[(ti << 2) + u][tj << 2] = *(float4*)s2row;
        }
        __syncthreads();

        // ---- phase 2: o += S2 * V ; z += rowsum(S2) ----
        #pragma unroll 4
        for (int jb = 0; jb < 16; ++jb) {
            float sv[4][4], vv[4][4];
            #pragma unroll
            for (int u = 0; u < 4; ++u)
                *(float4*)sv[u] = *(const float4*)&S2[(ti << 2) + u][jb << 2];
            #pragma unroll
            for (int w = 0; w < 4; ++w)
                *(float4*)vv[w] = *(const float4*)&Vs[(jb << 2) + w][tj << 2];
            #pragma unroll
            for (int u = 0; u < 4; ++u)
                #pragma unroll
                for (int w = 0; w < 4; ++w)
                    #pragma unroll
                    for (int c = 0; c < 4; ++c)
                        oacc[u][c] += sv[u][w] * vv[w][c];
            if (tj == 0) {   // only wave 0 lanes 0-15 pay for z
                #pragma unroll
                for (int u = 0; u < 4; ++u)
                    zacc[u] += sv[u][0] + sv[u][1] + sv[u][2] + sv[u][3];
            }
        }
    }

    if (tj == 0) {
        #pragma unroll
        for (int u = 0; u < 4; ++u) Zrow[(ti << 2) + u] = zacc[u];
    }
    __syncthreads();

    // ---- epilogue: out = o / (z + eps) ----
    float* odst = og + base + (size_t)qt * BQ * HD;
    #pragma unroll
    for (int u = 0; u < 4; ++u) {
        float inv = 1.f / (Zrow[(ti << 2) + u] + 1e-6f);
        float4 res;
        res.x = oacc[u][0] * inv;
        res.y = oacc[u][1] * inv;
        res.z = oacc[u][2] * inv;
        res.w = oacc[u][3] * inv;
        *(float4*)&odst[((ti << 2) + u) * HD + (tj << 2)] = res;
    }
}

extern "C" void kernel_launch(void* const* d_in, const int* in_sizes, int n_in,
                              void* d_out, int out_size, void* d_ws, size_t ws_size,
                              hipStream_t stream) {
    const float* q = (const float*)d_in[0];
    const float* k = (const float*)d_in[1];
    const float* v = (const float*)d_in[2];
    float* out = (float*)d_out;

    dim3 grid(SEQ / BQ, 4 * 16);   // (32 q-tiles, 64 heads)
    dim3 block(256);
    rebased_fp32_kernel<<<grid, block, 0, stream>>>(q, k, v, out);
}

// Round 2
// 276.147 us; speedup vs baseline: 4.6492x; 4.6492x over previous
//
#include <hip/hip_runtime.h>

// ReBASED parallel attention via bf16 MFMA, flash-style causal, squared scores.
// B=4 H=16 S=2048 D=64 fp32 in/out. grid=(16 q-tiles, 64 heads), block=256 (4 waves).
// Per block: BQ=128 q-rows; iterate BK=64 k-rows; S=Q·K^T via mfma_16x16x32_bf16,
// square+mask -> P (bf16, LDS roundtrip), O += P·V, z += P·1 (extra MFMA, ones-B).

#define SEQ 2048
#define HD  64
#define BQ  128
#define BK  64
#define LDS_S 72   // padded stride (shorts): 144B rows -> 16B aligned, 2-way-free reads

using bf16x8 = __attribute__((ext_vector_type(8))) short;
using f32x4  = __attribute__((ext_vector_type(4))) float;

__device__ inline unsigned short f2bf(float x) {
    union { float f; unsigned u; } v; v.f = x;
    unsigned r = v.u + 0x7FFFu + ((v.u >> 16) & 1u);   // RNE
    return (unsigned short)(r >> 16);
}

__global__ __launch_bounds__(256, 2)
void rebased_mfma_kernel(const float* __restrict__ qg,
                         const float* __restrict__ kg,
                         const float* __restrict__ vg,
                         float* __restrict__ og) {
    __shared__ __align__(16) unsigned short Qs[BQ][LDS_S];  // Q bf16, row-major, scaled
    __shared__ __align__(16) unsigned short Ks[BK][LDS_S];  // K bf16, row-major
    __shared__ __align__(16) unsigned short Vst[HD][LDS_S]; // V^T bf16: Vst[d][col]
    __shared__ __align__(16) unsigned short Ps[BQ][LDS_S];  // P=S^2 masked, row-major

    const int t    = threadIdx.x;
    const int lane = t & 63;
    const int w    = t >> 6;        // wave 0..3 -> rows [w*32, w*32+32)
    const int li   = lane & 15;
    const int qd   = lane >> 4;     // quad 0..3
    const int qt   = (int)gridDim.x - 1 - (int)blockIdx.x;  // big blocks first
    const int head = blockIdx.y;
    const size_t base = (size_t)head * SEQ * HD;

    // ---- stage Q tile (128x64 fp32 -> bf16, scale 0.125 folded) ----
    {
        const float4* qsrc = (const float4*)(qg + base + (size_t)qt * BQ * HD);
        #pragma unroll
        for (int l = 0; l < 8; ++l) {
            int f = t + l * 256;
            int row = f >> 4;
            int d4 = (f & 15) << 2;
            float4 val = qsrc[f];
            unsigned lo = f2bf(val.x * 0.125f) | ((unsigned)f2bf(val.y * 0.125f) << 16);
            unsigned hi = f2bf(val.z * 0.125f) | ((unsigned)f2bf(val.w * 0.125f) << 16);
            unsigned* dst = (unsigned*)&Qs[row][d4];
            dst[0] = lo; dst[1] = hi;
        }
    }

    f32x4 oacc[2][4];
    f32x4 zacc[2];
    #pragma unroll
    for (int mt = 0; mt < 2; ++mt) {
        zacc[mt] = (f32x4){0.f, 0.f, 0.f, 0.f};
        #pragma unroll
        for (int nd = 0; nd < 4; ++nd) oacc[mt][nd] = (f32x4){0.f, 0.f, 0.f, 0.f};
    }
    bf16x8 ones;
    #pragma unroll
    for (int i = 0; i < 8; ++i) ones[i] = (short)0x3F80;   // bf16 1.0

    const int ktmax = 2 * qt + 1;
    for (int kt = 0; kt <= ktmax; ++kt) {
        __syncthreads();   // prev PV reads done (and Q staged, on kt==0)

        // ---- stage K tile (64x64 -> bf16 row-major) ----
        {
            const float4* ksrc = (const float4*)(kg + base + (size_t)kt * BK * HD);
            #pragma unroll
            for (int l = 0; l < 4; ++l) {
                int f = t + l * 256;
                int row = f >> 4;
                int d4 = (f & 15) << 2;
                float4 val = ksrc[f];
                unsigned lo = f2bf(val.x) | ((unsigned)f2bf(val.y) << 16);
                unsigned hi = f2bf(val.z) | ((unsigned)f2bf(val.w) << 16);
                unsigned* dst = (unsigned*)&Ks[row][d4];
                dst[0] = lo; dst[1] = hi;
            }
        }
        // ---- stage V tile transposed: Vst[d][col]; paired rows -> b32 writes ----
        {
            const float4* vsrc = (const float4*)(vg + base + (size_t)kt * BK * HD);
            int d4g = t & 15;
            int rp  = t >> 4;
            #pragma unroll
            for (int p = 0; p < 2; ++p) {
                int r0 = p * 32 + rp * 2;
                float4 v0 = vsrc[r0 * 16 + d4g];
                float4 v1 = vsrc[(r0 + 1) * 16 + d4g];
                float a0[4] = {v0.x, v0.y, v0.z, v0.w};
                float a1[4] = {v1.x, v1.y, v1.z, v1.w};
                int d4 = d4g << 2;
                #pragma unroll
                for (int j = 0; j < 4; ++j) {
                    unsigned pk = (unsigned)f2bf(a0[j]) | ((unsigned)f2bf(a1[j]) << 16);
                    *(unsigned*)&Vst[d4 + j][r0] = pk;   // r0 even -> 4B aligned
                }
            }
        }
        __syncthreads();

        // ---- QK^T: wave w computes S rows [w*32,+32) x 64 cols ----
        f32x4 sacc[2][4];
        #pragma unroll
        for (int mt = 0; mt < 2; ++mt)
            #pragma unroll
            for (int nt = 0; nt < 4; ++nt) sacc[mt][nt] = (f32x4){0.f, 0.f, 0.f, 0.f};

        #pragma unroll
        for (int ks = 0; ks < 2; ++ks) {
            int kb = qd * 8 + ks * 32;
            bf16x8 af[2], bfr[4];
            af[0] = *(const bf16x8*)&Qs[w * 32      + li][kb];
            af[1] = *(const bf16x8*)&Qs[w * 32 + 16 + li][kb];
            #pragma unroll
            for (int nt = 0; nt < 4; ++nt)
                bfr[nt] = *(const bf16x8*)&Ks[nt * 16 + li][kb];
            #pragma unroll
            for (int mt = 0; mt < 2; ++mt)
                #pragma unroll
                for (int nt = 0; nt < 4; ++nt)
                    sacc[mt][nt] = __builtin_amdgcn_mfma_f32_16x16x32_bf16(
                        af[mt], bfr[nt], sacc[mt][nt], 0, 0, 0);
        }

        // ---- square + causal mask + write P (bf16) to LDS ----
        {
            const int row0 = qt * BQ + w * 32 + qd * 4;  // global row of reg 0
            const int col0 = kt * BK + li;               // global col of nt 0
            #pragma unroll
            for (int mt = 0; mt < 2; ++mt)
                #pragma unroll
                for (int nt = 0; nt < 4; ++nt)
                    #pragma unroll
                    for (int r = 0; r < 4; ++r) {
                        float s = sacc[mt][nt][r];
                        float pv = (col0 + nt * 16 <= row0 + mt * 16 + r) ? s * s : 0.f;
                        Ps[w * 32 + mt * 16 + qd * 4 + r][nt * 16 + li] = f2bf(pv);
                    }
        }
        __syncthreads();

        // ---- PV: O += P·V, z += P·1 ----
        #pragma unroll
        for (int ks = 0; ks < 2; ++ks) {
            int kb = qd * 8 + ks * 32;
            bf16x8 af[2], bfr[4];
            af[0] = *(const bf16x8*)&Ps[w * 32      + li][kb];
            af[1] = *(const bf16x8*)&Ps[w * 32 + 16 + li][kb];
            #pragma unroll
            for (int nd = 0; nd < 4; ++nd)
                bfr[nd] = *(const bf16x8*)&Vst[nd * 16 + li][kb];
            #pragma unroll
            for (int mt = 0; mt < 2; ++mt)
                #pragma unroll
                for (int nd = 0; nd < 4; ++nd)
                    oacc[mt][nd] = __builtin_amdgcn_mfma_f32_16x16x32_bf16(
                        af[mt], bfr[nd], oacc[mt][nd], 0, 0, 0);
            zacc[0] = __builtin_amdgcn_mfma_f32_16x16x32_bf16(af[0], ones, zacc[0], 0, 0, 0);
            zacc[1] = __builtin_amdgcn_mfma_f32_16x16x32_bf16(af[1], ones, zacc[1], 0, 0, 0);
        }
    }

    // ---- epilogue: out = o / (z + eps) ----
    float* odst = og + base + (size_t)qt * BQ * HD;
    #pragma unroll
    for (int mt = 0; mt < 2; ++mt)
        #pragma unroll
        for (int r = 0; r < 4; ++r) {
            float inv = 1.f / (zacc[mt][r] + 1e-6f);
            int rowl = w * 32 + mt * 16 + qd * 4 + r;
            #pragma unroll
            for (int nd = 0; nd < 4; ++nd)
                odst[rowl * HD + nd * 16 + li] = oacc[mt][nd][r] * inv;
        }
}

extern "C" void kernel_launch(void* const* d_in, const int* in_sizes, int n_in,
                              void* d_out, int out_size, void* d_ws, size_t ws_size,
                              hipStream_t stream) {
    const float* q = (const float*)d_in[0];
    const float* k = (const float*)d_in[1];
    const float* v = (const float*)d_in[2];
    float* out = (float*)d_out;

    dim3 grid(SEQ / BQ, 4 * 16);   // 16 q-tiles x 64 heads
    dim3 block(256);
    rebased_mfma_kernel<<<grid, block, 0, stream>>>(q, k, v, out);
}

// Round 3
// 209.327 us; speedup vs baseline: 6.1333x; 1.3192x over previous
//
#include <hip/hip_runtime.h>
#include <hip/hip_bf16.h>

// ReBASED attention R3: S^T-orientation MFMA flash kernel.
// QK^T computed transposed (A=K, B=Q) so the x32-MFMA C-layout IS the A-layout
// of mfma_16x16x16bf16_1k for PV -> no P LDS roundtrip, no third barrier.
// Paired q-tiles (j, 15-j) -> uniform block work; double-buffered K/V staging
// with register prefetch. grid=(8,64) block=256 (4 waves), 2 blocks/CU.

#define SEQ 2048
#define HD  64
#define BQ  128
#define BK  64
#define LQ  72   // Qs/Ks stride in shorts (144B rows, b128-aligned cols)
#define LV  76   // Vst stride in shorts (152B rows, b64-aligned, spreads banks)

typedef __attribute__((ext_vector_type(8))) short bf16x8;
typedef __attribute__((ext_vector_type(4))) short bf16x4;
typedef __attribute__((ext_vector_type(4))) float f32x4;

__device__ inline unsigned packbf(float a, float b) {
    __hip_bfloat162 h = __float22bfloat162_rn(make_float2(a, b));  // a->low, b->high
    union { __hip_bfloat162 h2; unsigned u; } cv; cv.h2 = h; return cv.u;
}

__global__ __launch_bounds__(256, 2)
void rebased_r3_kernel(const float* __restrict__ qg,
                       const float* __restrict__ kg,
                       const float* __restrict__ vg,
                       float* __restrict__ og) {
    __shared__ __align__(16) unsigned short Qs[BQ][LQ];
    __shared__ __align__(16) unsigned short Ks[2][BK][LQ];
    __shared__ __align__(16) unsigned short Vst[2][HD][LV];

    const int t    = threadIdx.x;
    const int lane = t & 63;
    const int w    = t >> 6;        // wave: q-rows [w*32, w*32+32)
    const int li   = lane & 15;
    const int qd   = lane >> 4;     // quad
    const int pj   = blockIdx.x;    // 0..7 -> q-tile pair (15-pj, pj)
    const int head = blockIdx.y;
    const size_t base = (size_t)head * SEQ * HD;

    #pragma unroll
    for (int seg = 0; seg < 2; ++seg) {
        const int qt = seg ? pj : (15 - pj);
        const int ktmax = 2 * qt + 1;

        // ---- load Q tile + kt=0 K/V into registers ----
        float4 qreg[8], kreg[4], vreg[4];
        {
            const float4* qsrc = (const float4*)(qg + base + (size_t)qt * BQ * HD);
            #pragma unroll
            for (int l = 0; l < 8; ++l) qreg[l] = qsrc[t + l * 256];
            const float4* ksrc = (const float4*)(kg + base);
            const float4* vsrc = (const float4*)(vg + base);
            #pragma unroll
            for (int l = 0; l < 4; ++l) kreg[l] = ksrc[t + l * 256];
            const int d4g = t & 15, rp = t >> 4;
            #pragma unroll
            for (int p = 0; p < 2; ++p) {
                int r0 = p * 32 + rp * 2;
                vreg[2 * p]     = vsrc[r0 * 16 + d4g];
                vreg[2 * p + 1] = vsrc[(r0 + 1) * 16 + d4g];
            }
        }
        __syncthreads();   // prior segment's LDS reads complete

        // ---- write Q (scaled) and kt=0 K/V to LDS ----
        #pragma unroll
        for (int l = 0; l < 8; ++l) {
            int f = t + l * 256, row = f >> 4, d4 = (f & 15) << 2;
            unsigned* dst = (unsigned*)&Qs[row][d4];
            dst[0] = packbf(qreg[l].x * 0.125f, qreg[l].y * 0.125f);
            dst[1] = packbf(qreg[l].z * 0.125f, qreg[l].w * 0.125f);
        }
        #pragma unroll
        for (int l = 0; l < 4; ++l) {
            int row = (t >> 4) + l * 16, d4 = (t & 15) << 2;
            unsigned* dst = (unsigned*)&Ks[0][row][d4];
            dst[0] = packbf(kreg[l].x, kreg[l].y);
            dst[1] = packbf(kreg[l].z, kreg[l].w);
        }
        {
            const int d4g = t & 15, rp = t >> 4;
            #pragma unroll
            for (int p = 0; p < 2; ++p) {
                int r0 = p * 32 + rp * 2;
                float a0[4] = {vreg[2*p].x, vreg[2*p].y, vreg[2*p].z, vreg[2*p].w};
                float a1[4] = {vreg[2*p+1].x, vreg[2*p+1].y, vreg[2*p+1].z, vreg[2*p+1].w};
                #pragma unroll
                for (int j = 0; j < 4; ++j)
                    *(unsigned*)&Vst[0][d4g * 4 + j][r0] = packbf(a0[j], a1[j]);
            }
        }
        __syncthreads();

        f32x4 oacc[2][4];
        float zpart[2] = {0.f, 0.f};
        #pragma unroll
        for (int mt = 0; mt < 2; ++mt)
            #pragma unroll
            for (int nd = 0; nd < 4; ++nd) oacc[mt][nd] = (f32x4){0.f, 0.f, 0.f, 0.f};

        for (int kt = 0; kt <= ktmax; ++kt) {
            const int cur = kt & 1;

            // ---- prefetch kt+1 K/V into registers (latency hides under compute) ----
            if (kt < ktmax) {
                const float4* ksrc = (const float4*)(kg + base + (size_t)(kt + 1) * BK * HD);
                const float4* vsrc = (const float4*)(vg + base + (size_t)(kt + 1) * BK * HD);
                #pragma unroll
                for (int l = 0; l < 4; ++l) kreg[l] = ksrc[t + l * 256];
                const int d4g = t & 15, rp = t >> 4;
                #pragma unroll
                for (int p = 0; p < 2; ++p) {
                    int r0 = p * 32 + rp * 2;
                    vreg[2 * p]     = vsrc[r0 * 16 + d4g];
                    vreg[2 * p + 1] = vsrc[(r0 + 1) * 16 + d4g];
                }
            }

            const int qrow_min = qt * BQ + w * 32;
            const bool active   = (kt * BK <= qrow_min + 31);
            const bool needmask = (kt * BK + 63 > qrow_min);

            if (active) {
                // ---- S^T = K·Q^T : x32 MFMA, A=K-frag, B=Q-frag ----
                f32x4 stt[4][2];
                #pragma unroll
                for (int nk = 0; nk < 4; ++nk)
                    #pragma unroll
                    for (int mt = 0; mt < 2; ++mt) stt[nk][mt] = (f32x4){0.f,0.f,0.f,0.f};
                #pragma unroll
                for (int ks = 0; ks < 2; ++ks) {
                    const int kb = ks * 32 + qd * 8;
                    bf16x8 kf[4], qf[2];
                    #pragma unroll
                    for (int nk = 0; nk < 4; ++nk)
                        kf[nk] = *(const bf16x8*)&Ks[cur][nk * 16 + li][kb];
                    #pragma unroll
                    for (int mt = 0; mt < 2; ++mt)
                        qf[mt] = *(const bf16x8*)&Qs[w * 32 + mt * 16 + li][kb];
                    #pragma unroll
                    for (int nk = 0; nk < 4; ++nk)
                        #pragma unroll
                        for (int mt = 0; mt < 2; ++mt)
                            stt[nk][mt] = __builtin_amdgcn_mfma_f32_16x16x32_bf16(
                                kf[nk], qf[mt], stt[nk][mt], 0, 0, 0);
                }

                // ---- square + mask + pack: C-layout of S^T == A-layout for x16 MFMA ----
                unsigned pk[4][2][2];
                #pragma unroll
                for (int nk = 0; nk < 4; ++nk) {
                    const int kcb = kt * BK + nk * 16 + qd * 4;
                    #pragma unroll
                    for (int mt = 0; mt < 2; ++mt) {
                        const int qrow = qrow_min + mt * 16 + li;
                        float p[4];
                        #pragma unroll
                        for (int r = 0; r < 4; ++r) {
                            float s = stt[nk][mt][r];
                            if (needmask && (kcb + r > qrow)) s = 0.f;
                            p[r] = s * s;
                        }
                        zpart[mt] += (p[0] + p[1]) + (p[2] + p[3]);
                        pk[nk][mt][0] = packbf(p[0], p[1]);
                        pk[nk][mt][1] = packbf(p[2], p[3]);
                    }
                }

                // ---- O += P·V : x16 MFMA, A=P (in regs), B=V^T from LDS ----
                #pragma unroll
                for (int ks16 = 0; ks16 < 4; ++ks16) {
                    bf16x4 av[2];
                    #pragma unroll
                    for (int mt = 0; mt < 2; ++mt) {
                        union { unsigned u[2]; bf16x4 v; } cv;
                        cv.u[0] = pk[ks16][mt][0]; cv.u[1] = pk[ks16][mt][1];
                        av[mt] = cv.v;
                    }
                    #pragma unroll
                    for (int nd = 0; nd < 4; ++nd) {
                        bf16x4 vf = *(const bf16x4*)&Vst[cur][nd * 16 + li][ks16 * 16 + qd * 4];
                        #pragma unroll
                        for (int mt = 0; mt < 2; ++mt)
                            oacc[mt][nd] = __builtin_amdgcn_mfma_f32_16x16x16bf16_1k(
                                av[mt], vf, oacc[mt][nd], 0, 0, 0);
                    }
                }
            }

            // ---- write prefetched kt+1 into the other buffer ----
            if (kt < ktmax) {
                const int nb = cur ^ 1;
                #pragma unroll
                for (int l = 0; l < 4; ++l) {
                    int row = (t >> 4) + l * 16, d4 = (t & 15) << 2;
                    unsigned* dst = (unsigned*)&Ks[nb][row][d4];
                    dst[0] = packbf(kreg[l].x, kreg[l].y);
                    dst[1] = packbf(kreg[l].z, kreg[l].w);
                }
                const int d4g = t & 15, rp = t >> 4;
                #pragma unroll
                for (int p = 0; p < 2; ++p) {
                    int r0 = p * 32 + rp * 2;
                    float a0[4] = {vreg[2*p].x, vreg[2*p].y, vreg[2*p].z, vreg[2*p].w};
                    float a1[4] = {vreg[2*p+1].x, vreg[2*p+1].y, vreg[2*p+1].z, vreg[2*p+1].w};
                    #pragma unroll
                    for (int j = 0; j < 4; ++j)
                        *(unsigned*)&Vst[nb][d4g * 4 + j][r0] = packbf(a0[j], a1[j]);
                }
            }
            __syncthreads();
        }

        // ---- epilogue: z reduce (quads) + divide + store ----
        float* odst = og + base + (size_t)qt * BQ * HD;
        #pragma unroll
        for (int mt = 0; mt < 2; ++mt) {
            float zf = zpart[mt];
            zf += __shfl_xor(zf, 16, 64);
            zf += __shfl_xor(zf, 32, 64);   // all lanes: z for qrow = mt*16 + li
            #pragma unroll
            for (int r = 0; r < 4; ++r) {
                float zr = __shfl(zf, qd * 4 + r, 64);
                float inv = 1.f / (zr + 1e-6f);
                int row = w * 32 + mt * 16 + qd * 4 + r;
                #pragma unroll
                for (int nd = 0; nd < 4; ++nd)
                    odst[row * HD + nd * 16 + li] = oacc[mt][nd][r] * inv;
            }
        }
    }
}

extern "C" void kernel_launch(void* const* d_in, const int* in_sizes, int n_in,
                              void* d_out, int out_size, void* d_ws, size_t ws_size,
                              hipStream_t stream) {
    const float* q = (const float*)d_in[0];
    const float* k = (const float*)d_in[1];
    const float* v = (const float*)d_in[2];
    float* out = (float*)d_out;

    dim3 grid(8, 64);    // 8 uniform q-tile pairs x 64 heads = 512 blocks = 2/CU
    dim3 block(256);
    rebased_r3_kernel<<<grid, block, 0, stream>>>(q, k, v, out);
}